// Round 12
// baseline (64.629 us; speedup 1.0000x reference)
//
#include <hip/hip_runtime.h>

// 8-tap reconstruction filters (sym4-style), float32.
#define LO0 0.23037781330885523f
#define LO1 0.7148465705525415f
#define LO2 0.6308807679295904f
#define LO3 -0.02798376941698385f
#define LO4 -0.18703481171888114f
#define LO5 0.030841381835986965f
#define LO6 0.032883011666982945f
#define LO7 -0.010597401784997278f

#define HI0 -0.010597401784997278f
#define HI1 -0.032883011666982945f
#define HI2 0.030841381835986965f
#define HI3 0.18703481171888114f
#define HI4 -0.02798376941698385f
#define HI5 -0.6308807679295904f
#define HI6 0.7148465705525415f
#define HI7 -0.23037781330885523f

#define NT 256   // 4 waves/block; each wave owns 4 consecutive 1024-col tiles

// Per-tile (1024 cols) pair counts, base offset 0:
//   L1=19 L2=35 L3=67 L4=131 L5=258 L6=512; staged inputs = NP+3.
// Edge tile verified: max read index == len-1 at every level, no clamping.

__device__ __forceinline__ void synth_pair(
    float x0, float x1, float x2, float x3,
    float g0, float g1, float g2, float g3,
    float& e, float& o)
{
    e = x0 * LO6 + g0 * HI6;
    e = fmaf(x1, LO4, e); e = fmaf(g1, HI4, e);
    e = fmaf(x2, LO2, e); e = fmaf(g2, HI2, e);
    e = fmaf(x3, LO0, e); e = fmaf(g3, HI0, e);
    o = x0 * LO7 + g0 * HI7;
    o = fmaf(x1, LO5, o); o = fmaf(g1, HI5, o);
    o = fmaf(x2, LO3, o); o = fmaf(g2, HI3, o);
    o = fmaf(x3, LO1, o); o = fmaf(g3, HI1, o);
}

__device__ __forceinline__ void synth_group4_lds(
    const float* __restrict__ XB, const float* __restrict__ D,
    float* __restrict__ OB, int p0)
{
    float4 x0 = *reinterpret_cast<const float4*>(XB + p0);
    float4 x1 = *reinterpret_cast<const float4*>(XB + p0 + 4);
    float4 g0 = *reinterpret_cast<const float4*>(D + p0);
    float4 g1 = *reinterpret_cast<const float4*>(D + p0 + 4);
    float e0,o0,e1,o1,e2,o2,e3,o3;
    synth_pair(x0.x,x0.y,x0.z,x0.w, g0.x,g0.y,g0.z,g0.w, e0,o0);
    synth_pair(x0.y,x0.z,x0.w,x1.x, g0.y,g0.z,g0.w,g1.x, e1,o1);
    synth_pair(x0.z,x0.w,x1.x,x1.y, g0.z,g0.w,g1.x,g1.y, e2,o2);
    synth_pair(x0.w,x1.x,x1.y,x1.z, g0.w,g1.x,g1.y,g1.z, e3,o3);
    *reinterpret_cast<float4*>(OB + 2*p0)     = make_float4(e0,o0,e1,o1);
    *reinterpret_cast<float4*>(OB + 2*p0 + 4) = make_float4(e2,o2,e3,o3);
}

// 4 pairs with register-resident g[0..6]; plain stores (LDS or global).
__device__ __forceinline__ void synth_group4_reg(
    const float* __restrict__ XB, int p0, const float* g, float* __restrict__ OB)
{
    float4 x0 = *reinterpret_cast<const float4*>(XB + p0);
    float4 x1 = *reinterpret_cast<const float4*>(XB + p0 + 4);
    float e0,o0,e1,o1,e2,o2,e3,o3;
    synth_pair(x0.x,x0.y,x0.z,x0.w, g[0],g[1],g[2],g[3], e0,o0);
    synth_pair(x0.y,x0.z,x0.w,x1.x, g[1],g[2],g[3],g[4], e1,o1);
    synth_pair(x0.z,x0.w,x1.x,x1.y, g[2],g[3],g[4],g[5], e2,o2);
    synth_pair(x0.w,x1.x,x1.y,x1.z, g[3],g[4],g[5],g[6], e3,o3);
    *reinterpret_cast<float4*>(OB + 2*p0)     = make_float4(e0,o0,e1,o1);
    *reinterpret_cast<float4*>(OB + 2*p0 + 4) = make_float4(e2,o2,e3,o3);
}

template<int NP>
__device__ __forceinline__ void wave_level(
    const float* __restrict__ XB, const float* __restrict__ D,
    float* __restrict__ OB, int lane)
{
    constexpr int NVEC = NP & ~3;
    static_assert(NVEC <= 256, "one vec group per lane");
    if (4 * lane < NVEC) synth_group4_lds(XB, D, OB, 4 * lane);
    if constexpr (NVEC < NP) {
        int p = NVEC + lane;
        if (p < NP) {
            float e, o;
            synth_pair(XB[p],XB[p+1],XB[p+2],XB[p+3],
                       D[p],D[p+1],D[p+2],D[p+3], e, o);
            OB[2*p]   = e;
            OB[2*p+1] = o;
        }
    }
}

// ---- Pure-C++ staging (NO global_load_lds, NO inline asm) ----
// Global -> registers (issue early; compiler tracks the latency), then
// registers -> LDS via ds_write after the previous tile's compute.
struct StageRegs { float a0, g6, g5, g4a, g4b, g3a, g3b, g3c; };

__device__ __forceinline__ void stage_load(
    const float* pa, const float* pd6, const float* pd5, const float* pd4,
    const float* pd3, StageRegs& S, int lane)
{
    if (lane < 22) { S.a0 = pa[lane]; S.g6 = pd6[lane]; }
    if (lane < 38) S.g5 = pd5[lane];
    S.g4a = pd4[lane];
    if (lane < 6) S.g4b = pd4[64 + lane];
    S.g3a = pd3[lane];
    S.g3b = pd3[64 + lane];
    if (lane < 6) S.g3c = pd3[128 + lane];
}

__device__ __forceinline__ void stage_write(
    float* A, float* D6, float* D5, float* D4, float* D3,
    const StageRegs& S, int lane)
{
    if (lane < 22) { A[lane] = S.a0; D6[lane] = S.g6; }
    if (lane < 38) D5[lane] = S.g5;
    D4[lane] = S.g4a;
    if (lane < 6) D4[64 + lane] = S.g4b;
    D3[lane] = S.g3a;
    D3[64 + lane] = S.g3b;
    if (lane < 6) D3[128 + lane] = S.g3c;
}

struct Regs { float d2r[7], d2t[4], d1A[7], d1B[7]; };

__device__ __forceinline__ void load_regs(
    const float* pd2, const float* pd1, Regs& R, int lane)
{
#pragma unroll
    for (int j = 0; j < 7; ++j) R.d2r[j] = pd2[4 * lane + j];
    if (lane < 2) {
#pragma unroll
        for (int j = 0; j < 4; ++j) R.d2t[j] = pd2[256 + lane + j];
    }
#pragma unroll
    for (int j = 0; j < 7; ++j) R.d1A[j] = pd1[4 * lane + j];
#pragma unroll
    for (int j = 0; j < 7; ++j) R.d1B[j] = pd1[4 * lane + 256 + j];
}

// Full 6-level chain for one tile (R6-proven), L6 straight to global.
__device__ __forceinline__ void compute_tile(
    float* A, float* B, const float* D6, const float* D5, const float* D4,
    const float* D3, const Regs& R, float* orow, int lane)
{
    if (lane < 19) {                       // L1: 19 pairs
        float e, o;
        synth_pair(A[lane],A[lane+1],A[lane+2],A[lane+3],
                   D6[lane],D6[lane+1],D6[lane+2],D6[lane+3], e, o);
        B[2*lane] = e; B[2*lane+1] = o;
    }
    wave_level<35> (B, D5, A, lane);       // L2
    wave_level<67> (A, D4, B, lane);       // L3
    wave_level<131>(B, D3, A, lane);       // L4
    synth_group4_reg(A, 4 * lane, R.d2r, B);   // L5 vec (256 pairs)
    if (lane < 2) {                            // L5 tail (pairs 256,257)
        int p = 256 + lane;
        float e, o;
        synth_pair(A[p],A[p+1],A[p+2],A[p+3],
                   R.d2t[0],R.d2t[1],R.d2t[2],R.d2t[3], e, o);
        B[2*p] = e; B[2*p+1] = o;
    }
    synth_group4_reg(B, 4 * lane,       R.d1A, orow);   // L6 -> global
    synth_group4_reg(B, 4 * lane + 256, R.d1B, orow);
}

__global__ __launch_bounds__(NT, 4) void idwt_fused_kernel(
    const float* __restrict__ a,
    const float* __restrict__ d6, const float* __restrict__ d5,
    const float* __restrict__ d4, const float* __restrict__ d3,
    const float* __restrict__ d2, const float* __restrict__ d1,
    float* __restrict__ out)
{
    // SINGLE per-wave LDS set, restaged each tile via reg->ds_write.
    // LDS = 4*(264+520+24+40+72+136)*4 = 16896 B.
    __shared__ __align__(16) float sA[4][264];
    __shared__ __align__(16) float sB[4][520];
    __shared__ __align__(16) float sD6[4][24];
    __shared__ __align__(16) float sD5[4][40];
    __shared__ __align__(16) float sD4[4][72];
    __shared__ __align__(16) float sD3[4][136];

    const int wid  = threadIdx.x >> 6;
    const int lane = threadIdx.x & 63;
    const int wg   = blockIdx.x * 4 + wid;     // 0..8191
    const int row  = wg >> 6;                  // 128 rows (64 waves/row)
    const int col0 = (wg & 63) << 12;          // 64 waves/row * 4096 cols

    const float* ra  = a  + (long long)row * 4102   + (col0 >> 6);
    const float* rd6 = d6 + (long long)row * 4102   + (col0 >> 6);
    const float* rd5 = d5 + (long long)row * 8198   + (col0 >> 5);
    const float* rd4 = d4 + (long long)row * 16390  + (col0 >> 4);
    const float* rd3 = d3 + (long long)row * 32774  + (col0 >> 3);
    const float* rd2 = d2 + (long long)row * 65541  + (col0 >> 2);
    const float* rd1 = d1 + (long long)row * 131075 + (col0 >> 1);
    float* orow = out + (long long)row * 262144 + col0;

    StageRegs S;
    Regs R0, R1;

    // Tile 0: load + write-through immediately.
    stage_load(ra, rd6, rd5, rd4, rd3, S, lane);
    load_regs(rd2, rd1, R0, lane);
    stage_write(sA[wid], sD6[wid], sD5[wid], sD4[wid], sD3[wid], S, lane);

    // Per tile t: (1) issue next tile's global->reg loads (latency hides
    // under compute), (2) compute tile t from LDS, (3) ds_write the staged
    // regs into LDS for tile t+1. Same-wave LDS ops execute in order (the
    // WAR of step 3 over step 2's reads is safe); all waits are
    // compiler-inserted. No asm, no DMA, no barriers.
#define STEP(t, CUR, NXT, IS_LAST)                                            \
    {                                                                         \
        if (!(IS_LAST)) {                                                     \
            constexpr int u = (t) + 1;                                        \
            stage_load(ra + 16*u, rd6 + 16*u, rd5 + 32*u, rd4 + 64*u,         \
                       rd3 + 128*u, S, lane);                                 \
            load_regs(rd2 + 256*u, rd1 + 512*u, NXT, lane);                   \
        }                                                                     \
        compute_tile(sA[wid], sB[wid], sD6[wid], sD5[wid], sD4[wid],          \
                     sD3[wid], CUR, orow + 1024 * (t), lane);                 \
        if (!(IS_LAST))                                                       \
            stage_write(sA[wid], sD6[wid], sD5[wid], sD4[wid], sD3[wid],      \
                        S, lane);                                             \
    }

    STEP(0, R0, R1, false)
    STEP(1, R1, R0, false)
    STEP(2, R0, R1, false)
    STEP(3, R1, R0, true)
#undef STEP
}

extern "C" void kernel_launch(void* const* d_in, const int* in_sizes, int n_in,
                              void* d_out, int out_size, void* d_ws, size_t ws_size,
                              hipStream_t stream) {
    const float* a  = (const float*)d_in[0];  // (128, 4102)
    const float* d6 = (const float*)d_in[1];  // (128, 4102)
    const float* d5 = (const float*)d_in[2];  // (128, 8198)
    const float* d4 = (const float*)d_in[3];  // (128, 16390)
    const float* d3 = (const float*)d_in[4];  // (128, 32774)
    const float* d2 = (const float*)d_in[5];  // (128, 65541)
    const float* d1 = (const float*)d_in[6];  // (128, 131075)

    float* OUT = (float*)d_out;               // (128, 262144)

    dim3 block(NT);
    dim3 grid(2048);                          // 4 waves/block, 4 tiles/wave
    idwt_fused_kernel<<<grid, block, 0, stream>>>(a, d6, d5, d4, d3, d2, d1, OUT);
}

// Round 13
// 55.070 us; speedup vs baseline: 1.1736x; 1.1736x over previous
//
#include <hip/hip_runtime.h>

// 8-tap reconstruction filters (sym4-style), float32.
#define LO0 0.23037781330885523f
#define LO1 0.7148465705525415f
#define LO2 0.6308807679295904f
#define LO3 -0.02798376941698385f
#define LO4 -0.18703481171888114f
#define LO5 0.030841381835986965f
#define LO6 0.032883011666982945f
#define LO7 -0.010597401784997278f

#define HI0 -0.010597401784997278f
#define HI1 -0.032883011666982945f
#define HI2 0.030841381835986965f
#define HI3 0.18703481171888114f
#define HI4 -0.02798376941698385f
#define HI5 -0.6308807679295904f
#define HI6 0.7148465705525415f
#define HI7 -0.23037781330885523f

#define NT 256   // 4 waves; each wave owns an independent 1024-col output tile

typedef float vfloat4 __attribute__((ext_vector_type(4)));

// Per-wave pair counts (T=1024, K0w multiple of 1024 -> all ranges exact,
// base offset 0 at every level):
//   L1=19 L2=35 L3=67 L4=131 L5=258 L6=512; staged inputs = NP+3.
// Edge wave verified: max read index == len-1 at every level, no clamping.

__device__ __forceinline__ void synth_pair(
    float x0, float x1, float x2, float x3,
    float g0, float g1, float g2, float g3,
    float& e, float& o)
{
    e = x0 * LO6 + g0 * HI6;
    e = fmaf(x1, LO4, e); e = fmaf(g1, HI4, e);
    e = fmaf(x2, LO2, e); e = fmaf(g2, HI2, e);
    e = fmaf(x3, LO0, e); e = fmaf(g3, HI0, e);
    o = x0 * LO7 + g0 * HI7;
    o = fmaf(x1, LO5, o); o = fmaf(g1, HI5, o);
    o = fmaf(x2, LO3, o); o = fmaf(g2, HI3, o);
    o = fmaf(x3, LO1, o); o = fmaf(g3, HI1, o);
}

// 4 pairs from LDS X + LDS D, write 8 outputs (2x float4).
__device__ __forceinline__ void synth_group4_lds(
    const float* __restrict__ XB, const float* __restrict__ D,
    float* __restrict__ OB, int p0)
{
    float4 x0 = *reinterpret_cast<const float4*>(XB + p0);
    float4 x1 = *reinterpret_cast<const float4*>(XB + p0 + 4);
    float4 g0 = *reinterpret_cast<const float4*>(D + p0);
    float4 g1 = *reinterpret_cast<const float4*>(D + p0 + 4);
    float e0,o0,e1,o1,e2,o2,e3,o3;
    synth_pair(x0.x,x0.y,x0.z,x0.w, g0.x,g0.y,g0.z,g0.w, e0,o0);
    synth_pair(x0.y,x0.z,x0.w,x1.x, g0.y,g0.z,g0.w,g1.x, e1,o1);
    synth_pair(x0.z,x0.w,x1.x,x1.y, g0.z,g0.w,g1.x,g1.y, e2,o2);
    synth_pair(x0.w,x1.x,x1.y,x1.z, g0.w,g1.x,g1.y,g1.z, e3,o3);
    *reinterpret_cast<float4*>(OB + 2*p0)     = make_float4(e0,o0,e1,o1);
    *reinterpret_cast<float4*>(OB + 2*p0 + 4) = make_float4(e2,o2,e3,o3);
}

// 4 pairs with register-resident g[0..6], plain LDS output (L5 path).
__device__ __forceinline__ void synth_group4_reg(
    const float* __restrict__ XB, int p0, const float* g, float* __restrict__ OB)
{
    float4 x0 = *reinterpret_cast<const float4*>(XB + p0);
    float4 x1 = *reinterpret_cast<const float4*>(XB + p0 + 4);
    float e0,o0,e1,o1,e2,o2,e3,o3;
    synth_pair(x0.x,x0.y,x0.z,x0.w, g[0],g[1],g[2],g[3], e0,o0);
    synth_pair(x0.y,x0.z,x0.w,x1.x, g[1],g[2],g[3],g[4], e1,o1);
    synth_pair(x0.z,x0.w,x1.x,x1.y, g[2],g[3],g[4],g[5], e2,o2);
    synth_pair(x0.w,x1.x,x1.y,x1.z, g[3],g[4],g[5],g[6], e3,o3);
    *reinterpret_cast<float4*>(OB + 2*p0)     = make_float4(e0,o0,e1,o1);
    *reinterpret_cast<float4*>(OB + 2*p0 + 4) = make_float4(e2,o2,e3,o3);
}

// L6 path: register g, NONTEMPORAL stores to global (exonerated by R10:
// the R8-R11 failures were DMA-in-loop, present with AND without nt).
__device__ __forceinline__ void synth_group4_reg_nt(
    const float* __restrict__ XB, int p0, const float* g, float* __restrict__ OB)
{
    float4 x0 = *reinterpret_cast<const float4*>(XB + p0);
    float4 x1 = *reinterpret_cast<const float4*>(XB + p0 + 4);
    float e0,o0,e1,o1,e2,o2,e3,o3;
    synth_pair(x0.x,x0.y,x0.z,x0.w, g[0],g[1],g[2],g[3], e0,o0);
    synth_pair(x0.y,x0.z,x0.w,x1.x, g[1],g[2],g[3],g[4], e1,o1);
    synth_pair(x0.z,x0.w,x1.x,x1.y, g[2],g[3],g[4],g[5], e2,o2);
    synth_pair(x0.w,x1.x,x1.y,x1.z, g[3],g[4],g[5],g[6], e3,o3);
    vfloat4 r0 = {e0, o0, e1, o1};
    vfloat4 r1 = {e2, o2, e3, o3};
    __builtin_nontemporal_store(r0, reinterpret_cast<vfloat4*>(OB + 2*p0));
    __builtin_nontemporal_store(r1, reinterpret_cast<vfloat4*>(OB + 2*p0 + 4));
}

// Generic per-wave level: NVEC <= 256 -> one predicated vec group per lane
// plus a <=3-pair scalar tail.
template<int NP>
__device__ __forceinline__ void wave_level(
    const float* __restrict__ XB, const float* __restrict__ D,
    float* __restrict__ OB, int lane)
{
    constexpr int NVEC = NP & ~3;
    static_assert(NVEC <= 256, "one vec group per lane");
    if (4 * lane < NVEC) synth_group4_lds(XB, D, OB, 4 * lane);
    if constexpr (NVEC < NP) {
        int p = NVEC + lane;
        if (p < NP) {
            float e, o;
            synth_pair(XB[p],XB[p+1],XB[p+2],XB[p+3],
                       D[p],D[p+1],D[p+2],D[p+3], e, o);
            OB[2*p]   = e;
            OB[2*p+1] = o;
        }
    }
}

// Async global->LDS DMA (linear dest == wave-uniform base + lane*4).
// Issued exactly ONCE per buffer per kernel (DMA-in-loop is broken: R8-R11).
typedef const __attribute__((address_space(1))) unsigned int* as1_u32_cptr;
typedef __attribute__((address_space(3))) unsigned int* as3_u32_ptr;

__device__ __forceinline__ void stage_async_w(const float* __restrict__ g,
                                              float* __restrict__ l,
                                              int n, int lane)
{
    for (int i = lane; i < n; i += 64) {
        __builtin_amdgcn_global_load_lds((as1_u32_cptr)(g + i),
                                         (as3_u32_ptr)(l + i), 4, 0, 0);
    }
}

__global__ __launch_bounds__(NT) void idwt_fused_kernel(
    const float* __restrict__ a,
    const float* __restrict__ d6, const float* __restrict__ d5,
    const float* __restrict__ d4, const float* __restrict__ d3,
    const float* __restrict__ d2, const float* __restrict__ d1,
    float* __restrict__ out)
{
    // Per-wave regions; no cross-wave sharing -> ZERO barriers.
    // sA[w]: a-tile(22) -> L2 out(70) -> L4 out(262)
    // sB[w]: L1 out(38) -> L3 out(134) -> L5 out(516)
    // D2 and D1 live in registers only.
    // Total LDS = 4*(264+520+24+40+72+136)*4 = 16896 B -> 8 blocks/CU.
    __shared__ __align__(16) float sA[4][264];
    __shared__ __align__(16) float sB[4][520];
    __shared__ __align__(16) float sD6[4][24];
    __shared__ __align__(16) float sD5[4][40];
    __shared__ __align__(16) float sD4[4][72];
    __shared__ __align__(16) float sD3[4][136];

    const int row  = blockIdx.y;
    const int wid  = threadIdx.x >> 6;
    const int lane = threadIdx.x & 63;
    const int K0w  = blockIdx.x * 4096 + wid * 1024;

    const float* pa  = a  + (long long)row * 4102   + (K0w >> 6);
    const float* pd6 = d6 + (long long)row * 4102   + (K0w >> 6);
    const float* pd5 = d5 + (long long)row * 8198   + (K0w >> 5);
    const float* pd4 = d4 + (long long)row * 16390  + (K0w >> 4);
    const float* pd3 = d3 + (long long)row * 32774  + (K0w >> 3);
    const float* pd2 = d2 + (long long)row * 65541  + (K0w >> 2);
    const float* pd1 = d1 + (long long)row * 131075 + (K0w >> 1);

    // DMA-stage the LDS-destined tiles (once; never re-issued).
    stage_async_w(pa,  sA[wid],  22,  lane);
    stage_async_w(pd6, sD6[wid], 22,  lane);
    stage_async_w(pd5, sD5[wid], 38,  lane);
    stage_async_w(pd4, sD4[wid], 70,  lane);
    stage_async_w(pd3, sD3[wid], 134, lane);

    // Drain covers ONLY the DMA ops (d2/d1 issued after, compiler-tracked).
    asm volatile("s_waitcnt vmcnt(0)" ::: "memory");

    // d2/d1 register loads: latency hides under L1..L4 / L1..L5 compute;
    // compiler inserts the precise vmcnt waits before first use.
    float d2r[7];
#pragma unroll
    for (int j = 0; j < 7; ++j) d2r[j] = pd2[4 * lane + j];
    float d2t[4];
    if (lane < 2) {
#pragma unroll
        for (int j = 0; j < 4; ++j) d2t[j] = pd2[256 + lane + j];
    }
    float d1A[7], d1B[7];
#pragma unroll
    for (int j = 0; j < 7; ++j) d1A[j] = pd1[4 * lane + j];
#pragma unroll
    for (int j = 0; j < 7; ++j) d1B[j] = pd1[4 * lane + 256 + j];

    // ---- L1 (19 pairs, scalar, lanes 0..18) ----
    if (lane < 19) {
        float e, o;
        synth_pair(sA[wid][lane], sA[wid][lane+1], sA[wid][lane+2], sA[wid][lane+3],
                   sD6[wid][lane], sD6[wid][lane+1], sD6[wid][lane+2], sD6[wid][lane+3],
                   e, o);
        sB[wid][2*lane]   = e;
        sB[wid][2*lane+1] = o;
    }

    // ---- L2..L4: pure per-wave LDS chain, lgkmcnt-ordered, no barriers ----
    wave_level<35> (sB[wid], sD5[wid], sA[wid], lane);
    wave_level<67> (sA[wid], sD4[wid], sB[wid], lane);
    wave_level<131>(sB[wid], sD3[wid], sA[wid], lane);

    // ---- L5 (258 pairs): vec from D2 regs + 2-pair tail ----
    synth_group4_reg(sA[wid], 4 * lane, d2r, sB[wid]);
    if (lane < 2) {
        int p = 256 + lane;
        float e, o;
        synth_pair(sA[wid][p], sA[wid][p+1], sA[wid][p+2], sA[wid][p+3],
                   d2t[0], d2t[1], d2t[2], d2t[3], e, o);
        sB[wid][2*p]   = e;
        sB[wid][2*p+1] = o;
    }

    // ---- L6 (512 pairs): two vec groups from D1 regs, nt stores to global ----
    float* orow = out + (long long)row * 262144 + K0w;
    synth_group4_reg_nt(sB[wid], 4 * lane,       d1A, orow);
    synth_group4_reg_nt(sB[wid], 4 * lane + 256, d1B, orow);
}

extern "C" void kernel_launch(void* const* d_in, const int* in_sizes, int n_in,
                              void* d_out, int out_size, void* d_ws, size_t ws_size,
                              hipStream_t stream) {
    const float* a  = (const float*)d_in[0];  // (128, 4102)
    const float* d6 = (const float*)d_in[1];  // (128, 4102)
    const float* d5 = (const float*)d_in[2];  // (128, 8198)
    const float* d4 = (const float*)d_in[3];  // (128, 16390)
    const float* d3 = (const float*)d_in[4];  // (128, 32774)
    const float* d2 = (const float*)d_in[5];  // (128, 65541)
    const float* d1 = (const float*)d_in[6];  // (128, 131075)

    float* OUT = (float*)d_out;               // (128, 262144)

    dim3 block(NT);
    dim3 grid(64, 128);                       // 8192 blocks, 4 waves each
    idwt_fused_kernel<<<grid, block, 0, stream>>>(a, d6, d5, d4, d3, d2, d1, OUT);
}

// Round 14
// 50.613 us; speedup vs baseline: 1.2769x; 1.0881x over previous
//
#include <hip/hip_runtime.h>

// 8-tap reconstruction filters (sym4-style), float32.
#define LO0 0.23037781330885523f
#define LO1 0.7148465705525415f
#define LO2 0.6308807679295904f
#define LO3 -0.02798376941698385f
#define LO4 -0.18703481171888114f
#define LO5 0.030841381835986965f
#define LO6 0.032883011666982945f
#define LO7 -0.010597401784997278f

#define HI0 -0.010597401784997278f
#define HI1 -0.032883011666982945f
#define HI2 0.030841381835986965f
#define HI3 0.18703481171888114f
#define HI4 -0.02798376941698385f
#define HI5 -0.6308807679295904f
#define HI6 0.7148465705525415f
#define HI7 -0.23037781330885523f

#define NT 256   // 4 waves; each wave owns an independent 1024-col output tile

// Per-wave pair counts (T=1024, K0w multiple of 1024 -> all ranges exact,
// base offset 0 at every level):
//   L1=19 L2=35 L3=67 L4=131 L5=258 L6=512; staged inputs = NP+3.
// Edge wave verified: max read index == len-1 at every level, no clamping.

__device__ __forceinline__ void synth_pair(
    float x0, float x1, float x2, float x3,
    float g0, float g1, float g2, float g3,
    float& e, float& o)
{
    e = x0 * LO6 + g0 * HI6;
    e = fmaf(x1, LO4, e); e = fmaf(g1, HI4, e);
    e = fmaf(x2, LO2, e); e = fmaf(g2, HI2, e);
    e = fmaf(x3, LO0, e); e = fmaf(g3, HI0, e);
    o = x0 * LO7 + g0 * HI7;
    o = fmaf(x1, LO5, o); o = fmaf(g1, HI5, o);
    o = fmaf(x2, LO3, o); o = fmaf(g2, HI3, o);
    o = fmaf(x3, LO1, o); o = fmaf(g3, HI1, o);
}

// 4 pairs from LDS X + LDS D, write 8 outputs (2x float4).
__device__ __forceinline__ void synth_group4_lds(
    const float* __restrict__ XB, const float* __restrict__ D,
    float* __restrict__ OB, int p0)
{
    float4 x0 = *reinterpret_cast<const float4*>(XB + p0);
    float4 x1 = *reinterpret_cast<const float4*>(XB + p0 + 4);
    float4 g0 = *reinterpret_cast<const float4*>(D + p0);
    float4 g1 = *reinterpret_cast<const float4*>(D + p0 + 4);
    float e0,o0,e1,o1,e2,o2,e3,o3;
    synth_pair(x0.x,x0.y,x0.z,x0.w, g0.x,g0.y,g0.z,g0.w, e0,o0);
    synth_pair(x0.y,x0.z,x0.w,x1.x, g0.y,g0.z,g0.w,g1.x, e1,o1);
    synth_pair(x0.z,x0.w,x1.x,x1.y, g0.z,g0.w,g1.x,g1.y, e2,o2);
    synth_pair(x0.w,x1.x,x1.y,x1.z, g0.w,g1.x,g1.y,g1.z, e3,o3);
    *reinterpret_cast<float4*>(OB + 2*p0)     = make_float4(e0,o0,e1,o1);
    *reinterpret_cast<float4*>(OB + 2*p0 + 4) = make_float4(e2,o2,e3,o3);
}

// 4 pairs with register-resident g[0..6]; plain stores (LDS or global —
// plain dwordx4 is the proven-optimal store path; nt regressed, R13).
__device__ __forceinline__ void synth_group4_reg(
    const float* __restrict__ XB, int p0, const float* g, float* __restrict__ OB)
{
    float4 x0 = *reinterpret_cast<const float4*>(XB + p0);
    float4 x1 = *reinterpret_cast<const float4*>(XB + p0 + 4);
    float e0,o0,e1,o1,e2,o2,e3,o3;
    synth_pair(x0.x,x0.y,x0.z,x0.w, g[0],g[1],g[2],g[3], e0,o0);
    synth_pair(x0.y,x0.z,x0.w,x1.x, g[1],g[2],g[3],g[4], e1,o1);
    synth_pair(x0.z,x0.w,x1.x,x1.y, g[2],g[3],g[4],g[5], e2,o2);
    synth_pair(x0.w,x1.x,x1.y,x1.z, g[3],g[4],g[5],g[6], e3,o3);
    *reinterpret_cast<float4*>(OB + 2*p0)     = make_float4(e0,o0,e1,o1);
    *reinterpret_cast<float4*>(OB + 2*p0 + 4) = make_float4(e2,o2,e3,o3);
}

// Generic per-wave level: NVEC <= 256 -> one predicated vec group per lane
// plus a <=3-pair scalar tail.
template<int NP>
__device__ __forceinline__ void wave_level(
    const float* __restrict__ XB, const float* __restrict__ D,
    float* __restrict__ OB, int lane)
{
    constexpr int NVEC = NP & ~3;
    static_assert(NVEC <= 256, "one vec group per lane");
    if (4 * lane < NVEC) synth_group4_lds(XB, D, OB, 4 * lane);
    if constexpr (NVEC < NP) {
        int p = NVEC + lane;
        if (p < NP) {
            float e, o;
            synth_pair(XB[p],XB[p+1],XB[p+2],XB[p+3],
                       D[p],D[p+1],D[p+2],D[p+3], e, o);
            OB[2*p]   = e;
            OB[2*p+1] = o;
        }
    }
}

// Async global->LDS DMA (linear dest == wave-uniform base + lane*4).
// Issued exactly ONCE per buffer per kernel (DMA-in-loop is broken: R8-R11).
typedef const __attribute__((address_space(1))) unsigned int* as1_u32_cptr;
typedef __attribute__((address_space(3))) unsigned int* as3_u32_ptr;

__device__ __forceinline__ void stage_async_w(const float* __restrict__ g,
                                              float* __restrict__ l,
                                              int n, int lane)
{
    for (int i = lane; i < n; i += 64) {
        __builtin_amdgcn_global_load_lds((as1_u32_cptr)(g + i),
                                         (as3_u32_ptr)(l + i), 4, 0, 0);
    }
}

__global__ __launch_bounds__(NT) void idwt_fused_kernel(
    const float* __restrict__ a,
    const float* __restrict__ d6, const float* __restrict__ d5,
    const float* __restrict__ d4, const float* __restrict__ d3,
    const float* __restrict__ d2, const float* __restrict__ d1,
    float* __restrict__ out)
{
    // Per-wave regions; no cross-wave sharing -> ZERO barriers.
    // sA[w]: a-tile(22) -> L2 out(70) -> L4 out(262)
    // sB[w]: L1 out(38) -> L3 out(134) -> L5 out(516)
    // D2 and D1 live in registers only.
    // Total LDS = 4*(264+520+24+40+72+136)*4 = 16896 B -> 8 blocks/CU.
    __shared__ __align__(16) float sA[4][264];
    __shared__ __align__(16) float sB[4][520];
    __shared__ __align__(16) float sD6[4][24];
    __shared__ __align__(16) float sD5[4][40];
    __shared__ __align__(16) float sD4[4][72];
    __shared__ __align__(16) float sD3[4][136];

    const int row  = blockIdx.y;
    const int wid  = threadIdx.x >> 6;
    const int lane = threadIdx.x & 63;
    const int K0w  = blockIdx.x * 4096 + wid * 1024;

    const float* pa  = a  + (long long)row * 4102   + (K0w >> 6);
    const float* pd6 = d6 + (long long)row * 4102   + (K0w >> 6);
    const float* pd5 = d5 + (long long)row * 8198   + (K0w >> 5);
    const float* pd4 = d4 + (long long)row * 16390  + (K0w >> 4);
    const float* pd3 = d3 + (long long)row * 32774  + (K0w >> 3);
    const float* pd2 = d2 + (long long)row * 65541  + (K0w >> 2);
    const float* pd1 = d1 + (long long)row * 131075 + (K0w >> 1);

    // DMA-stage the LDS-destined tiles (once; never re-issued).
    stage_async_w(pa,  sA[wid],  22,  lane);
    stage_async_w(pd6, sD6[wid], 22,  lane);
    stage_async_w(pd5, sD5[wid], 38,  lane);
    stage_async_w(pd4, sD4[wid], 70,  lane);
    stage_async_w(pd3, sD3[wid], 134, lane);

    // Drain covers ONLY the 8 DMA ops.
    asm volatile("s_waitcnt vmcnt(0)" ::: "memory");

    // ---- L1 (19 pairs, scalar, lanes 0..18) ----
    if (lane < 19) {
        float e, o;
        synth_pair(sA[wid][lane], sA[wid][lane+1], sA[wid][lane+2], sA[wid][lane+3],
                   sD6[wid][lane], sD6[wid][lane+1], sD6[wid][lane+2], sD6[wid][lane+3],
                   e, o);
        sB[wid][2*lane]   = e;
        sB[wid][2*lane+1] = o;
    }

    // d2/d1 register loads issued here: ~900cy HBM latency hides under the
    // L2..L4 LDS chain; compiler inserts precise vmcnt waits before use.
    float d2r[7];
#pragma unroll
    for (int j = 0; j < 7; ++j) d2r[j] = pd2[4 * lane + j];
    float d2t[4];
    if (lane < 2) {
#pragma unroll
        for (int j = 0; j < 4; ++j) d2t[j] = pd2[256 + lane + j];
    }
    float d1A[7], d1B[7];
#pragma unroll
    for (int j = 0; j < 7; ++j) d1A[j] = pd1[4 * lane + j];
#pragma unroll
    for (int j = 0; j < 7; ++j) d1B[j] = pd1[4 * lane + 256 + j];

    // ---- L2..L4: pure per-wave LDS chain, lgkmcnt-ordered, no barriers ----
    wave_level<35> (sB[wid], sD5[wid], sA[wid], lane);
    wave_level<67> (sA[wid], sD4[wid], sB[wid], lane);
    wave_level<131>(sB[wid], sD3[wid], sA[wid], lane);

    // ---- L5 (258 pairs): vec from D2 regs + 2-pair tail ----
    synth_group4_reg(sA[wid], 4 * lane, d2r, sB[wid]);
    if (lane < 2) {
        int p = 256 + lane;
        float e, o;
        synth_pair(sA[wid][p], sA[wid][p+1], sA[wid][p+2], sA[wid][p+3],
                   d2t[0], d2t[1], d2t[2], d2t[3], e, o);
        sB[wid][2*p]   = e;
        sB[wid][2*p+1] = o;
    }

    // ---- L6 (512 pairs): two vec groups from D1 regs, plain stores ----
    float* orow = out + (long long)row * 262144 + K0w;
    synth_group4_reg(sB[wid], 4 * lane,       d1A, orow);
    synth_group4_reg(sB[wid], 4 * lane + 256, d1B, orow);
}

extern "C" void kernel_launch(void* const* d_in, const int* in_sizes, int n_in,
                              void* d_out, int out_size, void* d_ws, size_t ws_size,
                              hipStream_t stream) {
    const float* a  = (const float*)d_in[0];  // (128, 4102)
    const float* d6 = (const float*)d_in[1];  // (128, 4102)
    const float* d5 = (const float*)d_in[2];  // (128, 8198)
    const float* d4 = (const float*)d_in[3];  // (128, 16390)
    const float* d3 = (const float*)d_in[4];  // (128, 32774)
    const float* d2 = (const float*)d_in[5];  // (128, 65541)
    const float* d1 = (const float*)d_in[6];  // (128, 131075)

    float* OUT = (float*)d_out;               // (128, 262144)

    dim3 block(NT);
    dim3 grid(64, 128);                       // 8192 blocks, 4 waves each
    idwt_fused_kernel<<<grid, block, 0, stream>>>(a, d6, d5, d4, d3, d2, d1, OUT);
}